// Round 14
// baseline (18061.119 us; speedup 1.0000x reference)
//
#include <hip/hip_runtime.h>

#define H_  1024
#define B_  8
#define T_  2048
#define V_  256
#define NWG 256
#define NTH 512
#define WPS (B_ * H_ / 4)   // 2048 u64 words per transport slot

// workspace layout (bytes)
#define OFF_TRANS 0u            // [2][WPS] u64 transport = 32 KB
#define OFF_PART  (64u << 10)   // [T_] f32 per-timestep partial NLL = 8 KB
#define OFF_HS    (1u << 20)    // [T_][B_][256] u64 tagged h = 32 MB

typedef unsigned long long u64;
typedef unsigned u32;

__device__ __forceinline__ u64 agload64(const u64* p) {
  return __hip_atomic_load(p, __ATOMIC_RELAXED, __HIP_MEMORY_SCOPE_AGENT);
}
__device__ __forceinline__ void agstore64(u64* p, u64 v) {
  __hip_atomic_store(p, v, __ATOMIC_RELAXED, __HIP_MEMORY_SCOPE_AGENT);
}
__device__ __forceinline__ u32 f2bf(float f) {          // bf16, RNE
  u32 u = __builtin_bit_cast(u32, f);
  return (u + 0x7fffu + ((u >> 16) & 1u)) >> 16;
}
__device__ __forceinline__ u32 f2bf14(float f) {        // bf16 on 4-ULP grid
  u32 u = __builtin_bit_cast(u32, f);
  return ((u + 0x1FFFFu + ((u >> 18) & 1u)) >> 18) << 2;
}

// decode one tagged u64 -> 4 f32 (unit-0 halfword's 2 tag LSBs masked)
__device__ __forceinline__ float4 dec4(u64 v) {
  const u32 lo = (u32)v, hi = (u32)(v >> 32);
  float4 f;
  f.x = __builtin_bit_cast(float, (lo & 0xFFFCu) << 16);
  f.y = __builtin_bit_cast(float, lo & 0xFFFF0000u);
  f.z = __builtin_bit_cast(float, (hi & 0xFFFFu) << 16);
  f.w = __builtin_bit_cast(float, hi & 0xFFFF0000u);
  return f;
}

// ---- main persistent recurrence: round-12 structure with THROTTLED poll.
// Evidence (r4-r12): unthrottled agent-scope spin during the store-visibility
// window generates ~1 GB of fabric re-fetches and congests the path the
// producer stores cross (16.4 ms); the same transport with ~1us of work (r7:
// do_chunk) or (here) a calibrated first-retry sleep avoids the storm.
__global__ __launch_bounds__(NTH, 1)
void charrnn_lstm(const int* __restrict__ Xs, const float* __restrict__ W_ih,
                  const float* __restrict__ W_hh, const float* __restrict__ b_ih,
                  const float* __restrict__ b_hh, u64* __restrict__ hg64,
                  u64* __restrict__ hs)
{
  __shared__ float hstage[B_][H_];   // 32 KB
  __shared__ float Wis[16][V_];      // 16 KB
  __shared__ float gates_s[16][8];
  __shared__ float c_s[4][8];
  __shared__ float bias_s[16];
  __shared__ int   xw[8][32];        // 32-step window of Xs

  const int wg   = blockIdx.x;
  const int tid  = threadIdx.x;
  const int b_g  = wg & 7;    // batch whose h this WG dumps
  const int slot = wg >> 3;   // t%32 dump slot
  const int row  = tid >> 5;  // 0..15 : local gate-row (gate*4 + jj)
  const int seg  = tid & 31;  // 0..31 : k-segment

  // W_hh slice -> registers: 32 floats/thread
  const int rg = (row >> 2) * H_ + wg * 4 + (row & 3);
  float4 wreg[8];
  #pragma unroll
  for (int q = 0; q < 8; ++q)
    wreg[q] = *(const float4*)&W_hh[(size_t)rg * H_ + seg * 4 + q * 128];

  // one-time W_ih slice -> LDS
  for (int i = tid; i < 16 * (V_ / 4); i += NTH) {
    int rl = i >> 6;
    int kq = i & 63;
    int rr = (rl >> 2) * H_ + wg * 4 + (rl & 3);
    *(float4*)&Wis[rl][kq * 4] = *(const float4*)&W_ih[(size_t)rr * V_ + kq * 4];
  }
  if (tid < 16) {
    int rr = (tid >> 2) * H_ + wg * 4 + (tid & 3);
    bias_s[tid] = b_ih[rr] + b_hh[rr];
  }
  if (tid < 32) c_s[tid >> 3][tid & 7] = 0.f;
  __syncthreads();

  const bool dumper = ((tid >> 8) == (b_g & 1));   // this thread holds batch b_g
  const int  dsel   = b_g >> 1;                    // which v[i] carries it

  for (int t = 0; t < T_; ++t) {
    // ---- 1. throttled tag-poll of h(t-1): 4 x b64, 2-LSB tag ----
    const u64* hb = hg64 + (size_t)((t + 1) & 1) * WPS;
    const u32 tagp = (u32)t & 3u;
    u64 v[4];
    int first = 1;
    for (;;) {
      bool ok = true;
      #pragma unroll
      for (int i = 0; i < 4; ++i) v[i] = agload64(&hb[i * NTH + tid]);
      #pragma unroll
      for (int i = 0; i < 4; ++i) ok &= (((u32)v[i] & 3u) == tagp);
      if (ok) break;
      // first miss: long sleep (~0.65us) covering the visibility window;
      // later misses: short. Late WGs hit on sweep 1 and never sleep.
      // (s_sleep operand must be a compile-time constant.)
      if (first) __builtin_amdgcn_s_sleep(24);
      else       __builtin_amdgcn_s_sleep(8);
      first = 0;
    }
    // capture this step's dump word via compile-time-indexed select (no scratch)
    u64 dv = v[0];
    if (dsel == 1) dv = v[1];
    else if (dsel == 2) dv = v[2];
    else if (dsel == 3) dv = v[3];
    const bool dumpit = (t > 0) && (((t - 1) & 31) == slot) && dumper;

    #pragma unroll
    for (int i = 0; i < 4; ++i) {
      const int idx = i * NTH + tid;          // word index 0..2047
      const int b = idx >> 8, u4 = idx & 255;
      *(float4*)&hstage[b][u4 * 4] = dec4(v[i]);
    }
    if ((t & 31) == 0 && tid < 256) {   // refresh 32-step Xs window
      const int b = tid >> 5, tt = t + (tid & 31);
      xw[b][tid & 31] = (tt < T_) ? Xs[b * T_ + tt] : 0;
    }
    __syncthreads();   // B1: hstage = h(t-1)

    // ---- 2. gate partial dots: thread (row, seg), 8 q-iters x 8 batches ----
    float4 acc[8];
    #pragma unroll
    for (int b = 0; b < 8; ++b) acc[b] = make_float4(0.f, 0.f, 0.f, 0.f);
    #pragma unroll
    for (int q = 0; q < 8; ++q) {
      const int k0 = seg * 4 + q * 128;
      const float4 w = wreg[q];
      #pragma unroll
      for (int b = 0; b < 8; ++b) {
        const float4 h4 = *(const float4*)&hstage[b][k0];
        acc[b].x = fmaf(w.x, h4.x, acc[b].x);
        acc[b].y = fmaf(w.y, h4.y, acc[b].y);
        acc[b].z = fmaf(w.z, h4.z, acc[b].z);
        acc[b].w = fmaf(w.w, h4.w, acc[b].w);
      }
    }
    float s[8];
    #pragma unroll
    for (int b = 0; b < 8; ++b) s[b] = (acc[b].x + acc[b].y) + (acc[b].z + acc[b].w);
    #pragma unroll
    for (int m = 1; m < 32; m <<= 1) {
      #pragma unroll
      for (int b = 0; b < 8; ++b) s[b] += __shfl_xor(s[b], m, 64);
    }
    if (seg < 8)   // b = seg
      gates_s[row][seg] = s[seg] + Wis[row][xw[seg][t & 31]] + bias_s[row];
    __syncthreads();   // B2: gates ready; all hstage reads done

    // ---- 3. c/h update + transport store + hs dump ----
    if (tid < 32) {
      const int jj = tid >> 3, b = tid & 7;
      float iv = gates_s[jj][b],      fv = gates_s[4 + jj][b];
      float gv = gates_s[8 + jj][b],  ov = gates_s[12 + jj][b];
      iv = 1.f / (1.f + __expf(-iv));
      fv = 1.f / (1.f + __expf(-fv));
      gv = tanhf(gv);
      ov = 1.f / (1.f + __expf(-ov));
      const float c = fv * c_s[jj][b] + iv * gv;
      c_s[jj][b] = c;
      const float h = ov * tanhf(c);
      const u32 full = f2bf(h);
      const u32 tagd = f2bf14(h) | ((u32)(t + 1) & 3u);
      const u32 r16 = ((jj & 3) == 0) ? tagd : full;   // jj==0 carries tag
      const u32 p1 = (u32)__shfl((int)r16, b + 8, 64);    // jj=1
      const u32 p2 = (u32)__shfl((int)r16, b + 16, 64);   // jj=2
      const u32 p3 = (u32)__shfl((int)r16, b + 24, 64);   // jj=3
      if (tid < 8) {
        const u64 w = (u64)r16 | ((u64)p1 << 16) | ((u64)p2 << 32) | ((u64)p3 << 48);
        agstore64(&hg64[(size_t)(t & 1) * WPS + tid * 256 + wg], w);
      }
    }
    if (dumpit)
      hs[((size_t)(t - 1) * B_ + b_g) * 256 + (tid & 255)] = dv;
  }

  // ---- tail: dump h(T-1) (slot 31 WGs, one per batch) ----
  if (slot == 31 && dumper) {
    const u64* hb = hg64 + (size_t)((T_ + 1) & 1) * WPS;
    const int idx = dsel * NTH + tid;
    u64 v = agload64(&hb[idx]);
    while (((u32)v & 3u) != ((u32)T_ & 3u)) {
      __builtin_amdgcn_s_sleep(8);
      v = agload64(&hb[idx]);
    }
    hs[((size_t)(T_ - 1) * B_ + b_g) * 256 + (tid & 255)] = v;
  }
}

// ---- deferred logits + softmax + NLL: one WG per timestep, all 8 batches.
__global__ __launch_bounds__(256, 4)
void loss_kernel(const int* __restrict__ ys, const float* __restrict__ b1,
                 const float* __restrict__ W1, const u64* __restrict__ hs,
                 float* __restrict__ partials) {
  __shared__ float hs_s[B_][H_];      // 32 KB
  __shared__ float logits_s[B_][V_];  //  8 KB
  const int tau = blockIdx.x;
  const int tid = threadIdx.x;

  #pragma unroll
  for (int b = 0; b < B_; ++b)
    *(float4*)&hs_s[b][tid * 4] = dec4(hs[((size_t)tau * B_ + b) * 256 + tid]);
  __syncthreads();

  const float* wrow = &W1[(size_t)tid * H_];
  float4 a[B_];
  #pragma unroll
  for (int b = 0; b < B_; ++b) a[b] = make_float4(0.f, 0.f, 0.f, 0.f);
  #pragma unroll 4
  for (int k = 0; k < 256; ++k) {
    const float4 w4 = *(const float4*)&wrow[k * 4];
    #pragma unroll
    for (int b = 0; b < B_; ++b) {
      const float4 h4 = *(const float4*)&hs_s[b][k * 4];   // LDS broadcast
      a[b].x = fmaf(w4.x, h4.x, a[b].x);
      a[b].y = fmaf(w4.y, h4.y, a[b].y);
      a[b].z = fmaf(w4.z, h4.z, a[b].z);
      a[b].w = fmaf(w4.w, h4.w, a[b].w);
    }
  }
  const float bb = b1[tid];
  #pragma unroll
  for (int b = 0; b < B_; ++b)
    logits_s[b][tid] = (a[b].x + a[b].y) + (a[b].z + a[b].w) + bb;
  __syncthreads();

  // wave w reduces batches w and 4+w
  const int wv = tid >> 6, lane = tid & 63;
  float acc = 0.f;
  #pragma unroll
  for (int h = 0; h < 2; ++h) {
    const int b = wv + h * 4;
    const float* lg = logits_s[b];
    float mx = fmaxf(fmaxf(lg[lane * 4], lg[lane * 4 + 1]),
                     fmaxf(lg[lane * 4 + 2], lg[lane * 4 + 3]));
    #pragma unroll
    for (int m = 1; m < 64; m <<= 1) mx = fmaxf(mx, __shfl_xor(mx, m, 64));
    float se = __expf(lg[lane * 4] - mx) + __expf(lg[lane * 4 + 1] - mx) +
               __expf(lg[lane * 4 + 2] - mx) + __expf(lg[lane * 4 + 3] - mx);
    #pragma unroll
    for (int m = 1; m < 64; m <<= 1) se += __shfl_xor(se, m, 64);
    if (lane == 0) acc += -(lg[ys[b * T_ + tau]] - mx - __logf(se));
  }
  __shared__ float pacc[4];
  if (lane == 0) pacc[wv] = acc;
  __syncthreads();
  if (tid == 0) partials[tau] = (pacc[0] + pacc[1]) + (pacc[2] + pacc[3]);
}

// ---- final mean: single WG, deterministic, no atomics ----
__global__ __launch_bounds__(256, 1)
void reduce_kernel(const float* __restrict__ partials, float* __restrict__ out) {
  const int tid = threadIdx.x;
  float acc = 0.f;
  #pragma unroll
  for (int i = 0; i < T_ / 256; ++i) acc += partials[i * 256 + tid];
  #pragma unroll
  for (int m = 1; m < 64; m <<= 1) acc += __shfl_xor(acc, m, 64);
  __shared__ float w[4];
  if ((tid & 63) == 0) w[tid >> 6] = acc;
  __syncthreads();
  if (tid == 0) out[0] = ((w[0] + w[1]) + (w[2] + w[3])) * (1.0f / (B_ * T_));
}

extern "C" void kernel_launch(void* const* d_in, const int* in_sizes, int n_in,
                              void* d_out, int out_size, void* d_ws, size_t ws_size,
                              hipStream_t stream) {
  const int*   Xs   = (const int*)d_in[0];
  const int*   ys   = (const int*)d_in[1];
  // d_in[2] = predict (always 0)
  const float* W_ih = (const float*)d_in[3];
  const float* W_hh = (const float*)d_in[4];
  const float* b_ih = (const float*)d_in[5];
  const float* b_hh = (const float*)d_in[6];
  const float* W1   = (const float*)d_in[7];
  const float* b1   = (const float*)d_in[8];
  float* out = (float*)d_out;

  u64*   hg64     = (u64*)((char*)d_ws + OFF_TRANS);
  float* partials = (float*)((char*)d_ws + OFF_PART);
  u64*   hs       = (u64*)((char*)d_ws + OFF_HS);

  // replay-safe: zero transport tags (tag0 == h(-1)=0)
  (void)hipMemsetAsync(hg64, 0, 2 * WPS * sizeof(u64), stream);

  void* args[] = { (void*)&Xs, (void*)&W_ih, (void*)&W_hh, (void*)&b_ih,
                   (void*)&b_hh, (void*)&hg64, (void*)&hs };
  hipError_t e = hipLaunchCooperativeKernel((const void*)charrnn_lstm, dim3(NWG),
                                            dim3(NTH), args, 0, stream);
  if (e != hipSuccess) {
    hipLaunchKernelGGL(charrnn_lstm, dim3(NWG), dim3(NTH), 0, stream,
                       Xs, W_ih, W_hh, b_ih, b_hh, hg64, hs);
  }

  loss_kernel<<<T_, 256, 0, stream>>>(ys, b1, W1, hs, partials);
  reduce_kernel<<<1, 256, 0, stream>>>(partials, out);
}

// Round 15
// 9544.925 us; speedup vs baseline: 1.8922x; 1.8922x over previous
//
#include <hip/hip_runtime.h>

#define H_  1024
#define B_  8
#define T_  2048
#define V_  256
#define NWG 256
#define NTH 512
#define WPS (B_ * H_ / 4)   // 2048 u64 words per transport slot

typedef unsigned long long u64;
typedef unsigned u32;

__device__ __forceinline__ u64 agload64(const u64* p) {
  return __hip_atomic_load(p, __ATOMIC_RELAXED, __HIP_MEMORY_SCOPE_AGENT);
}
__device__ __forceinline__ void agstore64(u64* p, u64 v) {
  __hip_atomic_store(p, v, __ATOMIC_RELAXED, __HIP_MEMORY_SCOPE_AGENT);
}
// full-precision bf16, RNE
__device__ __forceinline__ u32 f2bf(float f) {
  u32 u = __builtin_bit_cast(u32, f);
  return (u + 0x7fffu + ((u >> 16) & 1u)) >> 16;
}
// bf16 rounded (RNE) to 4-ULP grid: 2 LSBs free for the tag
__device__ __forceinline__ u32 f2bf14(float f) {
  u32 u = __builtin_bit_cast(u32, f);
  return ((u + 0x1FFFFu + ((u >> 18) & 1u)) >> 18) << 2;
}

__global__ __launch_bounds__(NTH, 1)
void charrnn_lstm(const int* __restrict__ Xs, const int* __restrict__ ys,
                  const float* __restrict__ W_ih, const float* __restrict__ W_hh,
                  const float* __restrict__ b_ih, const float* __restrict__ b_hh,
                  const float* __restrict__ W1, const float* __restrict__ b1,
                  float* __restrict__ out, u64* __restrict__ hg64)
{
  // EXACT round-7 structure (8.75 ms verified) with ONE change: transport
  // word layout b*256+wg -> wg*8+b, so each 64B line is written by a single
  // WG (was: 8 WGs on 8 XCDs per line -> 8 serialized remote line-updates
  // per step = suspected store-visibility floor).
  __shared__ float hstage[B_][H_];
  __shared__ float Wis[16][V_];
  __shared__ float stash[H_];
  __shared__ float logits_s[V_];
  __shared__ float gates_s[16][8];
  __shared__ float c_s[4][8];
  __shared__ float bias_s[16];
  __shared__ int   xw[8][32];      // 32-step window of Xs

  const int wg   = blockIdx.x;
  const int tid  = threadIdx.x;
  const int b_g  = wg & 7;    // batch whose loss this WG computes
  const int slot = wg >> 3;   // t%32 loss-position slot
  const int row  = tid >> 5;  // 0..15 : local gate-row (gate*4 + jj)
  const int seg  = tid & 31;  // 0..31 : k-segment

  // ---- W_hh slice -> registers: thread (row,seg) holds 32 weights ----
  const int rg = (row >> 2) * H_ + wg * 4 + (row & 3);
  float4 wreg[8];
  #pragma unroll
  for (int q = 0; q < 8; ++q)
    wreg[q] = *(const float4*)&W_hh[(size_t)rg * H_ + seg * 4 + q * 128];

  // ---- one-time staging of W_ih slice into LDS ----
  for (int i = tid; i < 16 * (V_ / 4); i += NTH) {
    int rl = i >> 6;
    int kq = i & 63;
    int rr = (rl >> 2) * H_ + wg * 4 + (rl & 3);
    *(float4*)&Wis[rl][kq * 4] = *(const float4*)&W_ih[(size_t)rr * V_ + kq * 4];
  }
  if (tid < 16) {
    int rr = (tid >> 2) * H_ + wg * 4 + (tid & 3);
    bias_s[tid] = b_ih[rr] + b_hh[rr];
  }
  if (tid < 32) c_s[tid >> 3][tid & 7] = 0.f;

  int   pending = 0, chunk = 0, ptau = 0;
  float wg_loss = 0.f;

  auto do_chunk = [&]() {   // 1/32 slice of output-projection + CE for (b_g, ptau)
    const int v_loc = tid >> 6, lane64 = tid & 63;
    const int vg = chunk * 8 + v_loc;
    const float* wrow = &W1[(size_t)vg * H_];
    float4 la = make_float4(0.f, 0.f, 0.f, 0.f);
    #pragma unroll
    for (int j = 0; j < 4; ++j) {
      const int k0 = lane64 * 4 + j * 256;
      const float4 w4 = *(const float4*)&wrow[k0];
      const float4 h4 = *(const float4*)&stash[k0];
      la.x = fmaf(w4.x, h4.x, la.x);
      la.y = fmaf(w4.y, h4.y, la.y);
      la.z = fmaf(w4.z, h4.z, la.z);
      la.w = fmaf(w4.w, h4.w, la.w);
    }
    float l = (la.x + la.y) + (la.z + la.w);
    #pragma unroll
    for (int m = 1; m < 64; m <<= 1) l += __shfl_xor(l, m, 64);
    if (lane64 == 0) logits_s[vg] = l + b1[vg];
    chunk++;
    if (chunk == 32) {
      __syncthreads();
      if (tid < 64) {
        float mx = -3.4e38f;
        #pragma unroll
        for (int i2 = 0; i2 < 4; ++i2) mx = fmaxf(mx, logits_s[tid * 4 + i2]);
        #pragma unroll
        for (int m = 1; m < 64; m <<= 1) mx = fmaxf(mx, __shfl_xor(mx, m, 64));
        float se = 0.f;
        #pragma unroll
        for (int i2 = 0; i2 < 4; ++i2) se += __expf(logits_s[tid * 4 + i2] - mx);
        #pragma unroll
        for (int m = 1; m < 64; m <<= 1) se += __shfl_xor(se, m, 64);
        if (tid == 0) {
          const float ly = logits_s[ys[b_g * T_ + ptau]];
          wg_loss += -(ly - mx - __logf(se));
        }
      }
      pending = 0;
      chunk = 0;
      __syncthreads();
    }
  };

  __syncthreads();

  for (int t = 0; t < T_; ++t) {
    // ---- 1. tag-poll of h(t-1): 4 x b64; tag = 2 LSBs of halfword 0 ----
    // word (wg', b) at hb[wg'*8+b] holds units wg'*4..+3 of batch b.
    const u64* hb = hg64 + (size_t)((t + 1) & 1) * WPS;
    const u32 tagp = (u32)t & 3u;
    u64 v[4];
    for (;;) {
      bool ok = true;
      #pragma unroll
      for (int i = 0; i < 4; ++i) v[i] = agload64(&hb[i * NTH + tid]);
      #pragma unroll
      for (int i = 0; i < 4; ++i) ok &= (((u32)v[i] & 3u) == tagp);
      if (ok) break;
      __builtin_amdgcn_s_sleep(1);
    }
    #pragma unroll
    for (int i = 0; i < 4; ++i) {
      const int idx = i * NTH + tid;          // word index 0..2047
      const int wgp = idx >> 3, b = idx & 7;  // word = (producer WG, batch)
      const u32 lo = (u32)v[i], hi = (u32)(v[i] >> 32);
      float4 f;
      f.x = __builtin_bit_cast(float, (lo & 0xFFFCu) << 16);  // tag bits masked
      f.y = __builtin_bit_cast(float, lo & 0xFFFF0000u);
      f.z = __builtin_bit_cast(float, (hi & 0xFFFFu) << 16);
      f.w = __builtin_bit_cast(float, hi & 0xFFFF0000u);
      *(float4*)&hstage[b][wgp * 4] = f;
    }
    if ((t & 31) == 0 && tid < 256) {   // refresh 32-step Xs window
      const int b = tid >> 5, tt = t + (tid & 31);
      xw[b][tid & 31] = (tt < T_) ? Xs[b * T_ + tt] : 0;
    }
    __syncthreads();   // B1: hstage = h(t-1)

    // ---- 2. gate partial dots: thread (row, seg), 8 q-iters x 8 batches ----
    float4 acc[8];
    #pragma unroll
    for (int b = 0; b < 8; ++b) acc[b] = make_float4(0.f, 0.f, 0.f, 0.f);
    #pragma unroll
    for (int q = 0; q < 8; ++q) {
      const int k0 = seg * 4 + q * 128;
      const float4 w = wreg[q];
      #pragma unroll
      for (int b = 0; b < 8; ++b) {
        const float4 h4 = *(const float4*)&hstage[b][k0];
        acc[b].x = fmaf(w.x, h4.x, acc[b].x);
        acc[b].y = fmaf(w.y, h4.y, acc[b].y);
        acc[b].z = fmaf(w.z, h4.z, acc[b].z);
        acc[b].w = fmaf(w.w, h4.w, acc[b].w);
      }
    }
    float s[8];
    #pragma unroll
    for (int b = 0; b < 8; ++b) s[b] = (acc[b].x + acc[b].y) + (acc[b].z + acc[b].w);
    #pragma unroll
    for (int m = 1; m < 32; m <<= 1) {
      #pragma unroll
      for (int b = 0; b < 8; ++b) s[b] += __shfl_xor(s[b], m, 64);
    }
    if (seg < 8)   // b = seg
      gates_s[row][seg] = s[seg] + Wis[row][xw[seg][t & 31]] + bias_s[row];
    __syncthreads();   // B2: gates ready; all hstage reads done

    // ---- 3. c/h update + one u64 store into THIS WG's private line ----
    if (tid < 32) {
      const int jj = tid >> 3, b = tid & 7;
      float iv = gates_s[jj][b],      fv = gates_s[4 + jj][b];
      float gv = gates_s[8 + jj][b],  ov = gates_s[12 + jj][b];
      iv = 1.f / (1.f + __expf(-iv));
      fv = 1.f / (1.f + __expf(-fv));
      gv = tanhf(gv);
      ov = 1.f / (1.f + __expf(-ov));
      const float c = fv * c_s[jj][b] + iv * gv;
      c_s[jj][b] = c;
      const float h = ov * tanhf(c);
      // unit jj==0 carries the 2-bit tag in its bf16 LSBs (RNE to 4-ULP grid)
      const u32 full = f2bf(h);
      const u32 tagd = f2bf14(h) | ((u32)(t + 1) & 3u);
      const u32 r16 = (jj == 0) ? tagd : full;
      const u32 p1 = (u32)__shfl((int)r16, b + 8, 64);    // jj=1
      const u32 p2 = (u32)__shfl((int)r16, b + 16, 64);   // jj=2
      const u32 p3 = (u32)__shfl((int)r16, b + 24, 64);   // jj=3
      if (tid < 8) {
        const u64 w = (u64)r16 | ((u64)p1 << 16) | ((u64)p2 << 32) | ((u64)p3 << 48);
        agstore64(&hg64[(size_t)(t & 1) * WPS + wg * 8 + tid], w);
      }
    }

    // ---- 4. stash h(tau) for this WG's loss position ----
    const int tau = t - 1;   // hstage holds h(t-1)
    const bool newst = (tau >= 0 && (tau & 31) == slot && !pending);
    if (newst) {
      for (int i = tid; i < H_; i += NTH) stash[i] = hstage[b_g][i];
    }
    if (newst) { pending = 1; chunk = 0; ptau = tau; }
    __syncthreads();   // stash ready; also fences hstage reuse vs next stage

    // ---- 5. fused-loss slice: fills the store-visibility window ----
    if (pending) do_chunk();
  }

  // ---- drain in-flight loss position ----
  while (pending) do_chunk();

  // ---- tau = T-1 (slot 31): poll-decode final h for batch b_g ----
  if (slot == 31) {
    const u64* hb = hg64 + (size_t)((T_ - 1) & 1) * WPS;
    if (tid < 256) {
      u64 w;
      do { w = agload64(&hb[tid * 8 + b_g]); }
      while (((u32)w & 3u) != ((u32)T_ & 3u));
      const u32 lo = (u32)w, hi = (u32)(w >> 32);
      float4 f;
      f.x = __builtin_bit_cast(float, (lo & 0xFFFCu) << 16);
      f.y = __builtin_bit_cast(float, lo & 0xFFFF0000u);
      f.z = __builtin_bit_cast(float, (hi & 0xFFFFu) << 16);
      f.w = __builtin_bit_cast(float, hi & 0xFFFF0000u);
      *(float4*)&stash[tid * 4] = f;
    }
    pending = 1; chunk = 0; ptau = T_ - 1;
    __syncthreads();
    while (pending) do_chunk();
  }

  if (tid == 0) atomicAdd(out, wg_loss * (1.0f / (B_ * T_)));
}

extern "C" void kernel_launch(void* const* d_in, const int* in_sizes, int n_in,
                              void* d_out, int out_size, void* d_ws, size_t ws_size,
                              hipStream_t stream) {
  const int*   Xs   = (const int*)d_in[0];
  const int*   ys   = (const int*)d_in[1];
  // d_in[2] = predict (always 0)
  const float* W_ih = (const float*)d_in[3];
  const float* W_hh = (const float*)d_in[4];
  const float* b_ih = (const float*)d_in[5];
  const float* b_hh = (const float*)d_in[6];
  const float* W1   = (const float*)d_in[7];
  const float* b1   = (const float*)d_in[8];
  float* out = (float*)d_out;

  u64* hg64 = (u64*)d_ws;   // [2][WPS] tagged 64-bit words

  // replay-safe: zeroed buffer == h(-1)=0 with tag 0; zero loss accumulator
  (void)hipMemsetAsync(d_out, 0, sizeof(float) * (size_t)out_size, stream);
  (void)hipMemsetAsync(d_ws, 0, 2 * WPS * sizeof(u64), stream);

  void* args[] = { (void*)&Xs, (void*)&ys, (void*)&W_ih, (void*)&W_hh,
                   (void*)&b_ih, (void*)&b_hh, (void*)&W1, (void*)&b1,
                   (void*)&out, (void*)&hg64 };
  hipError_t e = hipLaunchCooperativeKernel((const void*)charrnn_lstm, dim3(NWG),
                                            dim3(NTH), args, 0, stream);
  if (e != hipSuccess) {
    hipLaunchKernelGGL(charrnn_lstm, dim3(NWG), dim3(NTH), 0, stream,
                       Xs, ys, W_ih, W_hh, b_ih, b_hh, W1, b1, out, hg64);
  }
}